// Round 6
// baseline (3649.336 us; speedup 1.0000x reference)
//
#include <hip/hip_runtime.h>
#include <hip/hip_fp16.h>
#include <math.h>

#define HD   512
#define BB   256
#define TT   200
#define DIN  64
#define DOUT 64
#define NCLS 10
#define LIPC 0.909f

// ---------------- workspace layout (bytes) ----------------
#define GS_BYTES    407552
#define OFF2_WX     0
#define OFF2_WEMB   16384
#define OFF2_WF1    278528
#define OFF2_WF2    409600
#define OFF2_WOUT   540672
#define OFF2_WDEC   671744         // 256 kp x 64
#define NPACK       688128         // uints in W2
#define NFU         16384          // WfuP uints

// new-path extras (byte offsets from ws base)
#define OFF_GF      3227648ULL     // 512x512 f32
#define OFF_HF      4276224ULL
#define OFF_MF      5324800ULL
#define OFF_T64     6373376ULL     // 64x512 f32
#define OFF_F1F     6504448ULL
#define OFF_MDF     6635520ULL     // 512x64 f32
#define OFF_MCF     6766592ULL     // 512x16 f32
#define OFF_C1      6799360ULL
#define OFF_H0      6801408ULL
#define OFF_M0      6803456ULL
#define OFF_MD0     6805504ULL
#define OFF_MC0     6805760ULL
#define OFF_M2      6805824ULL     // 256x512 uint
#define OFF_G2      7330112ULL
#define OFF_F1P     7854400ULL     // 32x512 uint
#define OFF_MDP     7919936ULL     // 256x64 uint
#define OFF_MCP     7985472ULL     // 256x16 uint
#define OFF_WC16    8001856ULL     // 256x16 uint
#define OFF_E1H     8018240ULL     // 50944x512 half
#define OFF_EDF     60184896ULL    // 50944x64 f32
#define OFF_ECF     73226560ULL    // 50944x16 f32
#define WS_NEED     76486976ULL

__device__ __forceinline__ float lipswish(float x) {
    return LIPC * x / (1.0f + expf(-x));
}

typedef _Float16 h2_t __attribute__((ext_vector_type(2)));

__device__ __forceinline__ float fdot2u(unsigned a, unsigned b, float c) {
    return __builtin_amdgcn_fdot2(__builtin_bit_cast(h2_t, a),
                                  __builtin_bit_cast(h2_t, b), c, false);
}

__device__ __forceinline__ unsigned packh2(float a, float b) {
    __half2 hp = __floats2half2_rn(a, b);
    return __builtin_bit_cast(unsigned, hp);
}

__device__ __forceinline__ void pack_store(float v, unsigned* dstH, int j) {
    float other = __shfl_xor(v, 1, 64);
    if ((j & 1) == 0) dstH[j >> 1] = packh2(v, other);
}

// ---------------------------------------------------------------------------
// fp32 partial matvec
// ---------------------------------------------------------------------------
template<int K>
__device__ __forceinline__ void mv_part(const float* __restrict__ W,
                                        const float* src, float* part, int j)
{
    const int g = j >> 7, c = j & 127;
    const int kpg = K >> 2;
    const int k0 = g * kpg;
    const float4* __restrict__ W4 = (const float4*)W;
    float4 acc; acc.x = acc.y = acc.z = acc.w = 0.f;
#pragma unroll 2
    for (int k = k0; k < k0 + kpg; k += 4) {
        float4 a  = *(const float4*)(src + k);
        float4 w0 = W4[(size_t)(k + 0) * 128 + c];
        float4 w1 = W4[(size_t)(k + 1) * 128 + c];
        float4 w2 = W4[(size_t)(k + 2) * 128 + c];
        float4 w3 = W4[(size_t)(k + 3) * 128 + c];
        acc.x = fmaf(a.x, w0.x, acc.x); acc.y = fmaf(a.x, w0.y, acc.y);
        acc.z = fmaf(a.x, w0.z, acc.z); acc.w = fmaf(a.x, w0.w, acc.w);
        acc.x = fmaf(a.y, w1.x, acc.x); acc.y = fmaf(a.y, w1.y, acc.y);
        acc.z = fmaf(a.y, w1.z, acc.z); acc.w = fmaf(a.y, w1.w, acc.w);
        acc.x = fmaf(a.z, w2.x, acc.x); acc.y = fmaf(a.z, w2.y, acc.y);
        acc.z = fmaf(a.z, w2.z, acc.z); acc.w = fmaf(a.z, w2.w, acc.w);
        acc.x = fmaf(a.w, w3.x, acc.x); acc.y = fmaf(a.w, w3.y, acc.y);
        acc.z = fmaf(a.w, w3.z, acc.z); acc.w = fmaf(a.w, w3.w, acc.w);
    }
    *(float4*)(part + g * HD + 4 * c) = acc;
}
#define MV_REDUCE4(bias, j) ((bias)[j] + part[j] + part[HD + (j)] + part[2 * HD + (j)] + part[3 * HD + (j)])
#define MV_REDUCE8(bias, j) ((bias)[j] + ((part[j] + part[HD + (j)]) + (part[2 * HD + (j)] + part[3 * HD + (j)])) \
                           + ((part[4 * HD + (j)] + part[5 * HD + (j)]) + (part[6 * HD + (j)] + part[7 * HD + (j)])))

// ---------------------------------------------------------------------------
// device bodies shared by stageA and the fallback kernels
// ---------------------------------------------------------------------------
__device__ __forceinline__ void cvt_body(int bid, int j,
    const float* W_X, const float* W_emb, const float* Wf1, const float* Wf2,
    const float* W_out, const float* W_dec, unsigned* dst)
{
    size_t e = ((size_t)bid << 9) + j;
    const float* src; size_t off2; int csh;
    if      (bid < 32)   { src = W_X;   off2 = OFF2_WX;   csh = 9; }
    else if (bid < 544)  { src = W_emb; off2 = OFF2_WEMB; csh = 9; }
    else if (bid < 800)  { src = Wf1;   off2 = OFF2_WF1;  csh = 9; }
    else if (bid < 1056) { src = Wf2;   off2 = OFF2_WF2;  csh = 9; }
    else if (bid < 1312) { src = W_out; off2 = OFF2_WOUT; csh = 9; }
    else                 { src = W_dec; off2 = OFF2_WDEC; csh = 6; }
    size_t e2 = e - off2;
    size_t kp = e2 >> csh;
    size_t c  = e2 & (((size_t)1 << csh) - 1);
    size_t C  = (size_t)1 << csh;
    dst[e] = packh2(src[(2 * kp) * C + c], src[(2 * kp + 1) * C + c]);
}

__device__ __forceinline__ void fuse_body(int fb, int j,
    const float* W_X, const float* W_emb, const float* b_X, const float* b_emb,
    unsigned* WfuP, float* bias1)
{
    if (fb < 32) {
        const int k0 = fb * 2;
        float a0 = 0.f, a1 = 0.f;
#pragma unroll 4
        for (int n = 0; n < HD; ++n) {
            float w = W_emb[(size_t)(HD + n) * HD + j];
            a0 = fmaf(W_X[(size_t)k0 * HD + n],       w, a0);
            a1 = fmaf(W_X[(size_t)(k0 + 1) * HD + n], w, a1);
        }
        WfuP[(fb << 9) + j] = packh2(a0, a1);
    } else {
        float a0 = 0.f;
#pragma unroll 4
        for (int n = 0; n < HD; ++n)
            a0 = fmaf(b_X[n], W_emb[(size_t)(HD + n) * HD + j], a0);
        bias1[j] = a0 + b_emb[j];
    }
}

__device__ __forceinline__ void g_body(int t, int j, float* smem,
    const float* times, const float* W_noise, const float* b_noise,
    const float* Wg1, const float* bg1, const float* Wg2, const float* bg2,
    float* gs)
{
    float* tt   = smem;
    float* hh   = smem + HD;
    float* part = smem + 2 * HD;      // 4*HD floats
    float tv = times[t];
    tt[j] = tv * W_noise[j] + b_noise[j];
    __syncthreads();
    mv_part<HD>(Wg1, tt, part, j);
    __syncthreads();
    hh[j] = lipswish(MV_REDUCE4(bg1, j));
    __syncthreads();
    mv_part<HD>(Wg2, hh, part, j);
    __syncthreads();
    float dt = times[t + 1] - times[t];
    gs[t * HD + j] = MV_REDUCE4(bg2, j) * sqrtf(dt);
}

// tiled 8-row fp32 GEMM: C rows r0..r0+7 = A rows @ B (512x512). As = 8*HD LDS.
__device__ __forceinline__ void mm8_body(const float* __restrict__ A,
    const float* __restrict__ B, float* __restrict__ C, int r0, int j, float* As)
{
#pragma unroll
    for (int r = 0; r < 8; ++r) As[r * HD + j] = A[(size_t)(r0 + r) * HD + j];
    __syncthreads();
    float acc[8];
#pragma unroll
    for (int r = 0; r < 8; ++r) acc[r] = 0.f;
#pragma unroll 4
    for (int n = 0; n < HD; ++n) {
        float bv = B[(size_t)n * HD + j];
#pragma unroll
        for (int r = 0; r < 8; ++r) acc[r] = fmaf(As[r * HD + n], bv, acc[r]);
    }
#pragma unroll
    for (int r = 0; r < 8; ++r) C[(size_t)(r0 + r) * HD + j] = acc[r];
}

// ---------------------------------------------------------------------------
// stageA: cvt | fuse | g | G=We_y@Wf1 | H=Wf2@W_out | T64=W_X@We_x | h0
// grid = 1713 x 512
// ---------------------------------------------------------------------------
__global__ __launch_bounds__(512) void stageA(
    const float* __restrict__ W_X,  const float* __restrict__ W_emb,
    const float* __restrict__ Wf1,  const float* __restrict__ Wf2,
    const float* __restrict__ W_out, const float* __restrict__ W_dec,
    const float* __restrict__ b_X,  const float* __restrict__ b_emb,
    const float* __restrict__ times, const float* __restrict__ W_noise,
    const float* __restrict__ b_noise, const float* __restrict__ Wg1,
    const float* __restrict__ bg1, const float* __restrict__ Wg2,
    const float* __restrict__ bg2,
    const float* __restrict__ bf2, const float* __restrict__ b_out,
    unsigned* __restrict__ W2, unsigned* __restrict__ WfuP,
    float* __restrict__ bias1, float* __restrict__ gs,
    float* __restrict__ Gf, float* __restrict__ Hf,
    float* __restrict__ T64f, float* __restrict__ h0)
{
    __shared__ float smem[8 * HD];   // 16 KB
    const int bid = blockIdx.x;
    const int j   = threadIdx.x;
    if (bid < 1344) {
        cvt_body(bid, j, W_X, W_emb, Wf1, Wf2, W_out, W_dec, W2);
    } else if (bid < 1377) {
        fuse_body(bid - 1344, j, W_X, W_emb, b_X, b_emb, WfuP, bias1);
    } else if (bid < 1576) {
        g_body(bid - 1377, j, smem, times, W_noise, b_noise, Wg1, bg1, Wg2, bg2, gs);
    } else if (bid < 1640) {
        mm8_body(W_emb, Wf1, Gf, (bid - 1576) * 8, j, smem);
    } else if (bid < 1704) {
        mm8_body(Wf2, W_out, Hf, (bid - 1640) * 8, j, smem);
    } else if (bid < 1712) {
        mm8_body(W_X, W_emb + (size_t)HD * HD, T64f, (bid - 1704) * 8, j, smem);
    } else {
        smem[j] = bf2[j];
        __syncthreads();
        float acc = 0.f;
#pragma unroll 4
        for (int n = 0; n < HD; ++n) acc = fmaf(smem[n], W_out[(size_t)n * HD + j], acc);
        h0[j] = acc + b_out[j];
    }
}

// ---------------------------------------------------------------------------
// stageB: M=H@G | F1=T64@Wf1 | Md=H@Wd + Mc=H@Wc | m0 | md0/mc0 | c1
// grid = 139 x 512
// ---------------------------------------------------------------------------
__global__ __launch_bounds__(512) void stageB(
    const float* __restrict__ Gf, const float* __restrict__ Hf,
    const float* __restrict__ T64f, const float* __restrict__ Wf1,
    const float* __restrict__ W_dec, const float* __restrict__ W_cls,
    const float* __restrict__ bias1, const float* __restrict__ bf1,
    const float* __restrict__ h0,
    float* __restrict__ Mf, float* __restrict__ F1f,
    float* __restrict__ MdF, float* __restrict__ McF,
    float* __restrict__ m0, float* __restrict__ md0, float* __restrict__ mc0,
    float* __restrict__ c1)
{
    __shared__ float smem[8 * HD];   // 16 KB
    const int bid = blockIdx.x;
    const int j   = threadIdx.x;
    if (bid < 64) {
        mm8_body(Hf, Gf, Mf, bid * 8, j, smem);
    } else if (bid < 72) {
        mm8_body(T64f, Wf1, F1f, (bid - 64) * 8, j, smem);
    } else if (bid < 136) {
        const int r0 = (bid - 72) * 8;
#pragma unroll
        for (int r = 0; r < 8; ++r) smem[r * HD + j] = Hf[(size_t)(r0 + r) * HD + j];
        __syncthreads();
        {
            const int rr = j >> 6, c = j & 63;
            float acc = 0.f;
#pragma unroll 4
            for (int n = 0; n < HD; ++n)
                acc = fmaf(smem[rr * HD + n], W_dec[(size_t)n * 64 + c], acc);
            MdF[(size_t)(r0 + rr) * 64 + c] = acc;
        }
        if (j < 128) {
            const int rr = j >> 4, cc = j & 15;
            float acc = 0.f;
            if (cc < NCLS) {
#pragma unroll 4
                for (int n = 0; n < HD; ++n)
                    acc = fmaf(smem[rr * HD + n], W_cls[(size_t)n * NCLS + cc], acc);
            }
            McF[(size_t)(r0 + rr) * 16 + cc] = acc;
        }
    } else if (bid == 136) {
        smem[j] = h0[j];
        __syncthreads();
        float acc = 0.f;
#pragma unroll 4
        for (int n = 0; n < HD; ++n) acc = fmaf(smem[n], Gf[(size_t)n * HD + j], acc);
        m0[j] = acc;
    } else if (bid == 137) {
        smem[j] = h0[j];
        __syncthreads();
        if (j < 64) {
            float acc = 0.f;
#pragma unroll 4
            for (int n = 0; n < HD; ++n) acc = fmaf(smem[n], W_dec[(size_t)n * 64 + j], acc);
            md0[j] = acc;
        } else if (j < 80) {
            int c = j - 64;
            float acc = 0.f;
            if (c < NCLS) {
                for (int n = 0; n < HD; ++n) acc = fmaf(smem[n], W_cls[(size_t)n * NCLS + c], acc);
            }
            mc0[c] = acc;
        }
    } else {
        smem[j] = bias1[j];
        __syncthreads();
        float acc = 0.f;
#pragma unroll 4
        for (int n = 0; n < HD; ++n) acc = fmaf(smem[n], Wf1[(size_t)n * HD + j], acc);
        c1[j] = acc + bf1[j];
    }
}

// ---------------------------------------------------------------------------
// fallback-only standalone kernels (unchanged from verified R3/R4 path)
// ---------------------------------------------------------------------------
__global__ __launch_bounds__(512) void cvt_kernel(
    const float* __restrict__ W_X,  const float* __restrict__ W_emb,
    const float* __restrict__ Wf1,  const float* __restrict__ Wf2,
    const float* __restrict__ W_out, const float* __restrict__ W_dec,
    unsigned* __restrict__ dst)
{
    cvt_body(blockIdx.x, threadIdx.x, W_X, W_emb, Wf1, Wf2, W_out, W_dec, dst);
}

__global__ __launch_bounds__(512) void fuse_kernel(
    const float* __restrict__ W_X, const float* __restrict__ W_emb,
    const float* __restrict__ b_X, const float* __restrict__ b_emb,
    unsigned* __restrict__ WfuP, float* __restrict__ bias1)
{
    fuse_body(blockIdx.x, threadIdx.x, W_X, W_emb, b_X, b_emb, WfuP, bias1);
}

__global__ __launch_bounds__(512) void g_kernel(
    const float* __restrict__ times, const float* __restrict__ W_noise,
    const float* __restrict__ b_noise, const float* __restrict__ Wg1,
    const float* __restrict__ bg1, const float* __restrict__ Wg2,
    const float* __restrict__ bg2, float* __restrict__ gs)
{
    __shared__ float smem[6 * HD];
    g_body(blockIdx.x, threadIdx.x, smem, times, W_noise, b_noise,
           Wg1, bg1, Wg2, bg2, gs);
}

// ---------------------------------------------------------------------------
// packall: fp32 -> half2-pair packs for all new-path matrices. grid 592 x 512.
// ---------------------------------------------------------------------------
__global__ __launch_bounds__(512) void packall(
    const float* __restrict__ Mf, const float* __restrict__ Gf,
    const float* __restrict__ F1f, const float* __restrict__ MdF,
    const float* __restrict__ McF, const float* __restrict__ Wc,
    unsigned* __restrict__ M2, unsigned* __restrict__ G2,
    unsigned* __restrict__ F1P, unsigned* __restrict__ MdP,
    unsigned* __restrict__ McP, unsigned* __restrict__ Wc16)
{
    int bid = blockIdx.x, j = threadIdx.x;
    if (bid < 256) {
        int kp = bid;
        M2[(kp << 9) + j] = packh2(Mf[(size_t)(2 * kp) * HD + j], Mf[(size_t)(2 * kp + 1) * HD + j]);
    } else if (bid < 512) {
        int kp = bid - 256;
        G2[(kp << 9) + j] = packh2(Gf[(size_t)(2 * kp) * HD + j], Gf[(size_t)(2 * kp + 1) * HD + j]);
    } else if (bid < 544) {
        int kp = bid - 512;
        F1P[(kp << 9) + j] = packh2(F1f[(size_t)(2 * kp) * HD + j], F1f[(size_t)(2 * kp + 1) * HD + j]);
    } else if (bid < 576) {
        int e = (bid - 544) * 512 + j;
        int kp = e >> 6, c = e & 63;
        MdP[e] = packh2(MdF[(size_t)(2 * kp) * 64 + c], MdF[(size_t)(2 * kp + 1) * 64 + c]);
    } else if (bid < 584) {
        int e = (bid - 576) * 512 + j;
        int kp = e >> 4, c = e & 15;
        McP[e] = packh2(McF[(size_t)(2 * kp) * 16 + c], McF[(size_t)(2 * kp + 1) * 16 + c]);
    } else {
        int e = (bid - 584) * 512 + j;
        int kp = e >> 4, c = e & 15;
        float v0 = (c < NCLS) ? Wc[(size_t)(2 * kp) * NCLS + c] : 0.f;
        float v1 = (c < NCLS) ? Wc[(size_t)(2 * kp + 1) * NCLS + c] : 0.f;
        Wc16[e] = packh2(v0, v1);
    }
}

// ---------------------------------------------------------------------------
// eg: E1 = dW@G (half), Ed = dW@W_dec (f32), Ec = dW@W_cls16 (f32)
// ---------------------------------------------------------------------------
__global__ __launch_bounds__(512) void eg_kernel(
    const float* __restrict__ noise, const float* __restrict__ gs,
    const unsigned* __restrict__ G2, const unsigned* __restrict__ Wd2,
    const unsigned* __restrict__ Wc16,
    __half* __restrict__ E1h, float* __restrict__ Edf, float* __restrict__ Ecf)
{
    const int r0 = blockIdx.x * 32;
    const int t  = r0 >> 8;
    const int j  = threadIdx.x;
    __shared__ unsigned dWH[32 * 256];   // [rr*256 + kp]

#pragma unroll
    for (int i = 0; i < 16; ++i) {
        int e = i * 512 + j;
        int rr = e >> 8, kp = e & 255;
        float2 nz = *(const float2*)(noise + (size_t)(r0 + rr) * HD + 2 * kp);
        float2 gv = *(const float2*)(gs + (size_t)t * HD + 2 * kp);
        dWH[rr * 256 + kp] = packh2(nz.x * gv.x, nz.y * gv.y);
    }
    __syncthreads();

    {
        const int rg = j >> 7, cq = j & 127;
        float acc[8][4];
#pragma unroll
        for (int s = 0; s < 8; ++s)
#pragma unroll
            for (int c = 0; c < 4; ++c) acc[s][c] = 0.f;
#pragma unroll 2
        for (int kp = 0; kp < 256; ++kp) {
            uint4 w = *(const uint4*)(G2 + ((size_t)kp << 9) + (cq << 2));
#pragma unroll
            for (int s = 0; s < 8; ++s) {
                unsigned a = dWH[(rg * 8 + s) * 256 + kp];
                acc[s][0] = fdot2u(a, w.x, acc[s][0]);
                acc[s][1] = fdot2u(a, w.y, acc[s][1]);
                acc[s][2] = fdot2u(a, w.z, acc[s][2]);
                acc[s][3] = fdot2u(a, w.w, acc[s][3]);
            }
        }
#pragma unroll
        for (int s = 0; s < 8; ++s) {
            size_t row = r0 + rg * 8 + s;
            *(unsigned*)(E1h + row * HD + 4 * cq)     = packh2(acc[s][0], acc[s][1]);
            *(unsigned*)(E1h + row * HD + 4 * cq + 2) = packh2(acc[s][2], acc[s][3]);
        }
    }
    {
        const int rgrp = j >> 6, c = j & 63;
        float ad[4] = {0.f, 0.f, 0.f, 0.f};
#pragma unroll 4
        for (int kp = 0; kp < 256; ++kp) {
            unsigned wv = Wd2[(kp << 6) + c];
#pragma unroll
            for (int s = 0; s < 4; ++s)
                ad[s] = fdot2u(dWH[(rgrp * 4 + s) * 256 + kp], wv, ad[s]);
        }
#pragma unroll
        for (int s = 0; s < 4; ++s)
            Edf[(size_t)(r0 + rgrp * 4 + s) * 64 + c] = ad[s];
    }
    {
        const int rr = j >> 4, c = j & 15;
        float ac = 0.f;
#pragma unroll 4
        for (int kp = 0; kp < 256; ++kp)
            ac = fdot2u(dWH[rr * 256 + kp], Wc16[(kp << 4) + c], ac);
        Ecf[(size_t)(r0 + rr) * 16 + c] = ac;
    }
}

// ---------------------------------------------------------------------------
// dot2 matvec (fallback scan)
// ---------------------------------------------------------------------------
template<int KP>
__device__ __forceinline__ void mv_dot2(const unsigned* __restrict__ W2,
                                        const unsigned* actH, float* part, int j)
{
    const int g = j >> 6, o8 = (j & 63) << 3;
    constexpr int kpg = KP / 8;
    const int kp0 = g * kpg;
    float acc[8];
#pragma unroll
    for (int i = 0; i < 8; ++i) acc[i] = 0.f;
#pragma unroll 8
    for (int kp = kp0; kp < kp0 + kpg; ++kp) {
        unsigned ap = actH[kp];
        uint4 w0 = *(const uint4*)(W2 + ((size_t)kp << 9) + o8);
        uint4 w1 = *(const uint4*)(W2 + ((size_t)kp << 9) + o8 + 4);
        acc[0] = fdot2u(ap, w0.x, acc[0]);
        acc[1] = fdot2u(ap, w0.y, acc[1]);
        acc[2] = fdot2u(ap, w0.z, acc[2]);
        acc[3] = fdot2u(ap, w0.w, acc[3]);
        acc[4] = fdot2u(ap, w1.x, acc[4]);
        acc[5] = fdot2u(ap, w1.y, acc[5]);
        acc[6] = fdot2u(ap, w1.z, acc[6]);
        acc[7] = fdot2u(ap, w1.w, acc[7]);
    }
    float* pb = part + (g << 9) + o8;
    *(float4*)(pb)     = make_float4(acc[0], acc[1], acc[2], acc[3]);
    *(float4*)(pb + 4) = make_float4(acc[4], acc[5], acc[6], acc[7]);
}

// ---------------------------------------------------------------------------
// scan_fast pipeline helpers: chunk = 4 kp (8 uint4 loads, 32 fdot2).
// All indices compile-time after unroll -> stays in registers.
// ---------------------------------------------------------------------------
__device__ __forceinline__ void m_ld(uint4 (&buf)[8], const unsigned* bp, int c)
{
    const unsigned* p = bp + ((size_t)(c * 4) << 9);
#pragma unroll
    for (int r = 0; r < 4; ++r) {
        buf[2 * r]     = *(const uint4*)(p + r * 512);
        buf[2 * r + 1] = *(const uint4*)(p + r * 512 + 4);
    }
}

__device__ __forceinline__ void m_fd(const uint4 (&buf)[8], const unsigned* actH,
                                     int kp0, int c, float (&f)[8])
{
#pragma unroll
    for (int r = 0; r < 4; ++r) {
        unsigned ap = actH[kp0 + c * 4 + r];
        f[0] = fdot2u(ap, buf[2 * r].x, f[0]);
        f[1] = fdot2u(ap, buf[2 * r].y, f[1]);
        f[2] = fdot2u(ap, buf[2 * r].z, f[2]);
        f[3] = fdot2u(ap, buf[2 * r].w, f[3]);
        f[4] = fdot2u(ap, buf[2 * r + 1].x, f[4]);
        f[5] = fdot2u(ap, buf[2 * r + 1].y, f[5]);
        f[6] = fdot2u(ap, buf[2 * r + 1].z, f[6]);
        f[7] = fdot2u(ap, buf[2 * r + 1].w, f[7]);
    }
}

__device__ __forceinline__ float md4(const unsigned* actH, const unsigned* MdL,
                                     int kp0, int s, int mdc, float dmv)
{
#pragma unroll
    for (int r = 0; r < 4; ++r) {
        int kp = kp0 + s * 4 + r;
        dmv = fdot2u(actH[kp], MdL[(kp << 6) + mdc], dmv);
    }
    return dmv;
}

// ---------------------------------------------------------------------------
// scan_fast: conjugated state, pipelined M-GEMV.
// M phase: depth-3 register prefetch (3 chunk buffers), Md LDS work
// interleaved between chunks, E loads issued at step top.
// ---------------------------------------------------------------------------
__global__ __launch_bounds__(512) void scan_fast(
    const float* __restrict__ coeffs, const float* __restrict__ times,
    const int* __restrict__ mask,
    const unsigned* __restrict__ M2G, const unsigned* __restrict__ F1P,
    const unsigned* __restrict__ MdP, const unsigned* __restrict__ McP,
    const float* __restrict__ c1G, const float* __restrict__ m0G,
    const float* __restrict__ md0G, const float* __restrict__ mc0G,
    const float* __restrict__ GfG,
    const float* __restrict__ W_init, const float* __restrict__ b_init,
    const float* __restrict__ W_dec, const float* __restrict__ b_dec,
    const float* __restrict__ W_cls, const float* __restrict__ b_cls,
    const __half* __restrict__ E1h, const float* __restrict__ Edf,
    const float* __restrict__ Ecf,
    float* __restrict__ out)
{
    const int b = blockIdx.x;
    const int j = threadIdx.x;

    __shared__ __align__(16) unsigned F1L[32 * HD];     // 64 KB
    __shared__ __align__(16) unsigned MdL[32 * HD];     // 64 KB (256 kp x 64)
    __shared__ __align__(16) float    part[8 * HD];     // 16 KB
    __shared__ __align__(16) float    y0L[HD];
    __shared__ __align__(16) float    c1L[HD];
    __shared__ __align__(16) float    m0L[HD];
    __shared__ __align__(16) float    partd[512];
    __shared__ __align__(16) float    partw[256];
    __shared__ __align__(16) unsigned actH[HD / 2];
    __shared__ float    tl[TT];
    __shared__ float    md0L[64], bdecL[64];
    __shared__ float    vL[64];
    __shared__ float    avec[DIN];
    __shared__ unsigned avecH[DIN / 2];
    __shared__ float    mc0L[16], wL[16], wfinL[16];
    __shared__ int      lidx_s;

    if (j < TT) tl[j] = times[j];
#pragma unroll
    for (int i = 0; i < 32; ++i) F1L[(i << 9) + j] = F1P[(i << 9) + j];
#pragma unroll
    for (int i = 0; i < 32; ++i) MdL[(i << 9) + j] = MdP[(i << 9) + j];
    c1L[j] = c1G[j];
    m0L[j] = m0G[j];
    if (j < 64) { md0L[j] = md0G[j]; bdecL[j] = b_dec[j]; }
    if (j < 16) { mc0L[j] = mc0G[j]; wL[j] = 0.f; wfinL[j] = 0.f; }

    // per-row length
    {
        int m = 0;
        for (int t = j; t < TT; t += 512) m += mask[b * TT + t];
        part[j] = (float)m;
        __syncthreads();
        for (int s = 256; s > 0; s >>= 1) {
            if (j < s) part[j] += part[j + s];
            __syncthreads();
        }
        if (j == 0) lidx_s = (int)part[0] - 1;
        __syncthreads();
    }
    const int lidx = lidx_s;

    // y0 = a0@W_init + b_init
    if (j < DIN / 4)
        ((float4*)avec)[j] = ((const float4*)(coeffs + (size_t)b * (TT - 1) * 4 * DIN))[j];
    __syncthreads();
    mv_part<DIN>(W_init, avec, part, j);
    __syncthreads();
    y0L[j] = MV_REDUCE4(b_init, j);
    __syncthreads();

    // q0 = y0@G (fp32), v0 = y0@W_dec, w0 = y0@W_cls
    mv_part<HD>(GfG, y0L, part, j);
    if (j < 64) {
        float acc = 0.f;
#pragma unroll 4
        for (int n = 0; n < HD; ++n) acc = fmaf(y0L[n], W_dec[(size_t)n * 64 + j], acc);
        vL[j] = acc;
        out[((size_t)b * TT) * DOUT + j] = acc + b_dec[j];
    } else if (j >= 64 && j < 64 + NCLS) {
        int c = j - 64;
        float acc = 0.f;
#pragma unroll 4
        for (int n = 0; n < HD; ++n) acc = fmaf(y0L[n], W_cls[(size_t)n * NCLS + c], acc);
        wL[c] = acc;
    }
    __syncthreads();
    float q = part[j] + part[HD + j] + part[2 * HD + j] + part[3 * HD + j];
    if (j < 16 && lidx == 0) wfinL[j] = wL[j];
    __syncthreads();

    const int g8  = j >> 6;
    const int o8  = (j & 63) << 3;
    const int kp0 = g8 * 32;
    const int mdc = j & 63;
    const unsigned* bp = M2G + ((size_t)kp0 << 9) + o8;

    // ---- main scan ----
    for (int t = 0; t < TT - 1; ++t) {
        const size_t rbase = (size_t)t * BB + b;
        // early HBM loads (consumed after S3-phase reduce)
        unsigned short e1u = ((const unsigned short*)E1h)[rbase * HD + j];
        float edv = Edf[rbase * 64 + (j & 63)];
        float ecv = Ecf[rbase * 16 + (j & 15)];
        if (j < 32) {
            float2 a2 = ((const float2*)(coeffs + ((size_t)b * (TT - 1) + t) * 4 * DIN))[j];
            avecH[j] = packh2(a2.x, a2.y);
        }
        __syncthreads();   // S1
        {
            float sa = 0.f, sb = 0.f, sc = 0.f, sd = 0.f;
#pragma unroll
            for (int kp = 0; kp < 8; ++kp) {
                sa = fdot2u(avecH[kp],      F1L[((kp)      << 9) + j], sa);
                sb = fdot2u(avecH[kp + 8],  F1L[((kp + 8)  << 9) + j], sb);
                sc = fdot2u(avecH[kp + 16], F1L[((kp + 16) << 9) + j], sc);
                sd = fdot2u(avecH[kp + 24], F1L[((kp + 24) << 9) + j], sd);
            }
            float s = ((q + c1L[j]) + (sa + sb)) + (sc + sd);
            pack_store(lipswish(s), actH, j);
        }
        // prefetch first 3 chunks of M (addresses step-invariant, indep of actH)
        uint4 Ab[8], Bb[8], Cb[8];
        m_ld(Ab, bp, 0); m_ld(Bb, bp, 1); m_ld(Cb, bp, 2);
        __syncthreads();   // S2
        float f[8];
#pragma unroll
        for (int i = 0; i < 8; ++i) f[i] = 0.f;
        float dm0 = 0.f, dm1 = 0.f;
        m_fd(Ab, actH, kp0, 0, f); dm0 = md4(actH, MdL, kp0, 0, mdc, dm0); m_ld(Ab, bp, 3);
        m_fd(Bb, actH, kp0, 1, f); dm1 = md4(actH, MdL, kp0, 1, mdc, dm1); m_ld(Bb, bp, 4);
        m_fd(Cb, actH, kp0, 2, f); dm0 = md4(actH, MdL, kp0, 2, mdc, dm0); m_ld(Cb, bp, 5);
        m_fd(Ab, actH, kp0, 3, f); dm1 = md4(actH, MdL, kp0, 3, mdc, dm1); m_ld(Ab, bp, 6);
        m_fd(Bb, actH, kp0, 4, f); dm0 = md4(actH, MdL, kp0, 4, mdc, dm0); m_ld(Bb, bp, 7);
        m_fd(Cb, actH, kp0, 5, f); dm1 = md4(actH, MdL, kp0, 5, mdc, dm1);
        m_fd(Ab, actH, kp0, 6, f); dm0 = md4(actH, MdL, kp0, 6, mdc, dm0);
        m_fd(Bb, actH, kp0, 7, f); dm1 = md4(actH, MdL, kp0, 7, mdc, dm1);
        {
            float* pb2 = part + (g8 << 9) + o8;
            *(float4*)(pb2)     = make_float4(f[0], f[1], f[2], f[3]);
            *(float4*)(pb2 + 4) = make_float4(f[4], f[5], f[6], f[7]);
            partd[(g8 << 6) + mdc] = dm0 + dm1;
        }
        if (j < 256) {
            int gw = j >> 4, cw = j & 15;
            float wacc = 0.f;
#pragma unroll
            for (int i2 = 0; i2 < 16; ++i2) {
                int kp = gw * 16 + i2;
                wacc = fdot2u(actH[kp], McP[(kp << 4) + cw], wacc);
            }
            partw[(gw << 4) + cw] = wacc;
        }
        __syncthreads();   // S3
        {
            float dtv = tl[t + 1] - tl[t];
            float red = ((part[j] + part[HD + j]) + (part[2 * HD + j] + part[3 * HD + j]))
                      + ((part[4 * HD + j] + part[5 * HD + j]) + (part[6 * HD + j] + part[7 * HD + j]));
            q = q + dtv * (red + m0L[j]) + __half2float(__builtin_bit_cast(__half, e1u));
            if (j < 64) {
                float dv = 0.f;
#pragma unroll
                for (int g = 0; g < 8; ++g) dv += partd[(g << 6) + j];
                float vn = vL[j] + dtv * (dv + md0L[j]) + edv;
                vL[j] = vn;
                out[((size_t)b * TT + t + 1) * DOUT + j] = vn + bdecL[j];
            }
            if (j < 16) {
                float dw = 0.f;
#pragma unroll
                for (int g = 0; g < 16; ++g) dw += partw[(g << 4) + j];
                float wn = wL[j] + dtv * (dw + mc0L[j]) + ecv;
                wL[j] = wn;
                if (t + 1 == lidx) wfinL[j] = wn;
            }
        }
    }
    __syncthreads();
    if (j < NCLS)
        out[(size_t)BB * TT * DOUT + b * NCLS + j] = wfinL[j] + b_cls[j];
}

// ---------------------------------------------------------------------------
// FALLBACK scan (verified R3 kernel, used when ws is too small)
// ---------------------------------------------------------------------------
__device__ __forceinline__ void decode_store_d2(const unsigned* __restrict__ Wd2,
    const float* __restrict__ b_dec, const unsigned* yH, float* part, float* dscr,
    int j, float* __restrict__ outp)
{
    const int g = j >> 3, o8 = (j & 7) << 3;
    const int kp0 = g << 2;
    float acc[8];
#pragma unroll
    for (int i = 0; i < 8; ++i) acc[i] = 0.f;
#pragma unroll
    for (int kp = kp0; kp < kp0 + 4; ++kp) {
        unsigned ap = yH[kp];
        uint4 w0 = *(const uint4*)(Wd2 + ((size_t)kp << 6) + o8);
        uint4 w1 = *(const uint4*)(Wd2 + ((size_t)kp << 6) + o8 + 4);
        acc[0] = fdot2u(ap, w0.x, acc[0]);
        acc[1] = fdot2u(ap, w0.y, acc[1]);
        acc[2] = fdot2u(ap, w0.z, acc[2]);
        acc[3] = fdot2u(ap, w0.w, acc[3]);
        acc[4] = fdot2u(ap, w1.x, acc[4]);
        acc[5] = fdot2u(ap, w1.y, acc[5]);
        acc[6] = fdot2u(ap, w1.z, acc[6]);
        acc[7] = fdot2u(ap, w1.w, acc[7]);
    }
    float* pb = part + (g << 6) + o8;
    *(float4*)(pb)     = make_float4(acc[0], acc[1], acc[2], acc[3]);
    *(float4*)(pb + 4) = make_float4(acc[4], acc[5], acc[6], acc[7]);
    __syncthreads();
    {
        int o2 = j >> 6, col = j & 63;
        float s = 0.f;
#pragma unroll
        for (int i = 0; i < 8; ++i) s += part[((o2 << 3) + i) * 64 + col];
        dscr[(o2 << 6) + col] = s;
    }
    __syncthreads();
    if (j < DOUT) {
        float s = b_dec[j];
#pragma unroll
        for (int i = 0; i < 8; ++i) s += dscr[(i << 6) + j];
        outp[j] = s;
    }
}

__global__ __launch_bounds__(512) void scan_fb(
    const float* __restrict__ coeffs, const float* __restrict__ times,
    const float* __restrict__ noise, const float* __restrict__ bias1,
    const float* __restrict__ bf1, const float* __restrict__ bf2,
    const float* __restrict__ b_out,
    const float* __restrict__ W_init, const float* __restrict__ b_init,
    const float* __restrict__ b_dec,
    const float* __restrict__ W_cls, const float* __restrict__ b_cls,
    const int* __restrict__ mask, const float* __restrict__ gs,
    const unsigned* __restrict__ W2, const unsigned* __restrict__ WfuG,
    float* __restrict__ out)
{
    const int b = blockIdx.x;
    const int j = threadIdx.x;

    const unsigned* __restrict__ W_emb_2 = W2 + OFF2_WEMB;
    const unsigned* __restrict__ Wf1_2   = W2 + OFF2_WF1;
    const unsigned* __restrict__ Wf2_2   = W2 + OFF2_WF2;
    const unsigned* __restrict__ W_out_2 = W2 + OFF2_WOUT;
    const unsigned* __restrict__ W_dec_2 = W2 + OFF2_WDEC;

    __shared__ float    yF[HD];
    __shared__ unsigned yH[HD / 2];
    __shared__ unsigned actAH[HD / 2];
    __shared__ unsigned actBH[HD / 2];
    __shared__ unsigned avecH[DIN / 2];
    __shared__ unsigned WfuL[32 * HD];
    __shared__ float    part[8 * HD];
    __shared__ float    dscr[HD];
    __shared__ float    avec[DIN];
    __shared__ float    zfin[HD];
    __shared__ float    tl[TT];
    __shared__ int      last_idx_s;

    if (j < TT) tl[j] = times[j];
#pragma unroll
    for (int i = 0; i < 32; ++i) WfuL[i * 512 + j] = WfuG[i * 512 + j];
    {
        int m = 0;
        for (int t = j; t < TT; t += 512) m += mask[b * TT + t];
        part[j] = (float)m;
        __syncthreads();
        for (int s = 256; s > 0; s >>= 1) {
            if (j < s) part[j] += part[j + s];
            __syncthreads();
        }
        if (j == 0) last_idx_s = (int)part[0] - 1;
        __syncthreads();
    }
    const int last_idx = last_idx_s;

    if (j < DIN / 4)
        ((float4*)avec)[j] = ((const float4*)(coeffs + (size_t)b * (TT - 1) * 4 * DIN))[j];
    __syncthreads();
    mv_part<DIN>(W_init, avec, part, j);
    __syncthreads();
    {
        float y = MV_REDUCE4(b_init, j);
        yF[j] = y;
        pack_store(y, yH, j);
        if (last_idx == 0) zfin[j] = y;
    }
    __syncthreads();
    decode_store_d2(W_dec_2, b_dec, yH, part, dscr, j, out + ((size_t)b * TT) * DOUT);

    for (int t = 0; t < TT - 1; ++t) {
        if (j < DIN / 2) {
            float2 a2 = ((const float2*)(coeffs + ((size_t)b * (TT - 1) + t) * 4 * DIN))[j];
            avecH[j] = packh2(a2.x, a2.y);
        }
        __syncthreads();
        mv_dot2<HD / 2>(W_emb_2, yH, part, j);
        __syncthreads();
        {
            float s = MV_REDUCE8(bias1, j);
#pragma unroll
            for (int kp = 0; kp < 32; ++kp)
                s = fdot2u(avecH[kp], WfuL[(kp << 9) + j], s);
            pack_store(s, actAH, j);
        }
        __syncthreads();
        mv_dot2<HD / 2>(Wf1_2, actAH, part, j);
        __syncthreads();
        pack_store(lipswish(MV_REDUCE8(bf1, j)), actBH, j);
        __syncthreads();
        mv_dot2<HD / 2>(Wf2_2, actBH, part, j);
        __syncthreads();
        pack_store(MV_REDUCE8(bf2, j), actAH, j);
        __syncthreads();
        mv_dot2<HD / 2>(W_out_2, actAH, part, j);
        __syncthreads();
        {
            float dr = MV_REDUCE8(b_out, j);
            float dtv = tl[t + 1] - tl[t];
            float yn = yF[j] + dr * dtv
                     + gs[(size_t)t * HD + j] * noise[((size_t)t * BB + b) * HD + j];
            yF[j] = yn;
            pack_store(yn, yH, j);
            if (t + 1 == last_idx) zfin[j] = yn;
        }
        __syncthreads();
        decode_store_d2(W_dec_2, b_dec, yH, part, dscr, j,
                        out + ((size_t)b * TT + (t + 1)) * DOUT);
    }
    __syncthreads();
    {
        int c = j & 15, seg = j >> 4;
        float p = 0.f;
        if (c < NCLS) {
#pragma unroll
            for (int k = seg * 16; k < seg * 16 + 16; ++k)
                p = fmaf(zfin[k], W_cls[k * NCLS + c], p);
        }
        part[j] = p;
        __syncthreads();
        if (j < NCLS) {
            float s = b_cls[j];
#pragma unroll
            for (int sg = 0; sg < 32; ++sg) s += part[sg * 16 + j];
            out[(size_t)BB * TT * DOUT + b * NCLS + j] = s;
        }
    }
}

extern "C" void kernel_launch(void* const* d_in, const int* in_sizes, int n_in,
                              void* d_out, int out_size, void* d_ws, size_t ws_size,
                              hipStream_t stream)
{
    const float* coeffs  = (const float*)d_in[0];
    const float* times   = (const float*)d_in[1];
    const float* noise   = (const float*)d_in[2];
    const float* W_X     = (const float*)d_in[3];
    const float* b_X     = (const float*)d_in[4];
    const float* W_emb   = (const float*)d_in[5];
    const float* b_emb   = (const float*)d_in[6];
    const float* Wf1     = (const float*)d_in[7];
    const float* bf1     = (const float*)d_in[8];
    const float* Wf2     = (const float*)d_in[9];
    const float* bf2     = (const float*)d_in[10];
    const float* W_out   = (const float*)d_in[11];
    const float* b_out   = (const float*)d_in[12];
    const float* W_noise = (const float*)d_in[13];
    const float* b_noise = (const float*)d_in[14];
    const float* Wg1     = (const float*)d_in[15];
    const float* bg1     = (const float*)d_in[16];
    const float* Wg2     = (const float*)d_in[17];
    const float* bg2     = (const float*)d_in[18];
    const float* W_init  = (const float*)d_in[19];
    const float* b_init  = (const float*)d_in[20];
    const float* W_dec   = (const float*)d_in[21];
    const float* b_dec   = (const float*)d_in[22];
    const float* W_cls   = (const float*)d_in[23];
    const float* b_cls   = (const float*)d_in[24];
    const int*   mask    = (const int*)d_in[25];

    char* ws = (char*)d_ws;
    float*    gs    = (float*)ws;
    unsigned* W2    = (unsigned*)(ws + GS_BYTES);
    unsigned* WfuP  = W2 + NPACK;
    float*    bias1 = (float*)(W2 + NPACK + NFU);
    float*    out   = (float*)d_out;

    if (ws_size >= WS_NEED) {
        float*    Gf   = (float*)(ws + OFF_GF);
        float*    Hf   = (float*)(ws + OFF_HF);
        float*    Mf   = (float*)(ws + OFF_MF);
        float*    T64f = (float*)(ws + OFF_T64);
        float*    F1f  = (float*)(ws + OFF_F1F);
        float*    MdF  = (float*)(ws + OFF_MDF);
        float*    McF  = (float*)(ws + OFF_MCF);
        float*    c1   = (float*)(ws + OFF_C1);
        float*    h0   = (float*)(ws + OFF_H0);
        float*    m0   = (float*)(ws + OFF_M0);
        float*    md0  = (float*)(ws + OFF_MD0);
        float*    mc0  = (float*)(ws + OFF_MC0);
        unsigned* M2   = (unsigned*)(ws + OFF_M2);
        unsigned* G2   = (unsigned*)(ws + OFF_G2);
        unsigned* F1P  = (unsigned*)(ws + OFF_F1P);
        unsigned* MdP  = (unsigned*)(ws + OFF_MDP);
        unsigned* McP  = (unsigned*)(ws + OFF_MCP);
        unsigned* Wc16 = (unsigned*)(ws + OFF_WC16);
        __half*   E1h  = (__half*)(ws + OFF_E1H);
        float*    Edf  = (float*)(ws + OFF_EDF);
        float*    Ecf  = (float*)(ws + OFF_ECF);
        unsigned* Wd2  = W2 + OFF2_WDEC;

        stageA<<<dim3(1713), dim3(512), 0, stream>>>(
            W_X, W_emb, Wf1, Wf2, W_out, W_dec, b_X, b_emb,
            times, W_noise, b_noise, Wg1, bg1, Wg2, bg2, bf2, b_out,
            W2, WfuP, bias1, gs, Gf, Hf, T64f, h0);

        stageB<<<dim3(139), dim3(512), 0, stream>>>(
            Gf, Hf, T64f, Wf1, W_dec, W_cls, bias1, bf1, h0,
            Mf, F1f, MdF, McF, m0, md0, mc0, c1);

        packall<<<dim3(592), dim3(512), 0, stream>>>(Mf, Gf, F1f, MdF, McF, W_cls,
                                                     M2, G2, F1P, MdP, McP, Wc16);

        eg_kernel<<<dim3((TT - 1) * BB / 32), dim3(512), 0, stream>>>(
            noise, gs, G2, Wd2, Wc16, E1h, Edf, Ecf);

        scan_fast<<<dim3(BB), dim3(512), 0, stream>>>(
            coeffs, times, mask, M2, F1P, MdP, McP, c1, m0, md0, mc0,
            Gf, W_init, b_init, W_dec, b_dec, W_cls, b_cls,
            E1h, Edf, Ecf, out);
    } else {
        cvt_kernel<<<dim3(NPACK / 512), dim3(512), 0, stream>>>(
            W_X, W_emb, Wf1, Wf2, W_out, W_dec, W2);
        fuse_kernel<<<dim3(33), dim3(512), 0, stream>>>(
            W_X, W_emb, b_X, b_emb, WfuP, bias1);
        g_kernel<<<dim3(TT - 1), dim3(512), 0, stream>>>(
            times, W_noise, b_noise, Wg1, bg1, Wg2, bg2, gs);
        scan_fb<<<dim3(BB), dim3(512), 0, stream>>>(
            coeffs, times, noise, bias1, bf1, bf2, b_out,
            W_init, b_init, b_dec, W_cls, b_cls, mask, gs, W2, WfuP, out);
    }
}

// Round 8
// 3635.055 us; speedup vs baseline: 1.0039x; 1.0039x over previous
//
#include <hip/hip_runtime.h>
#include <hip/hip_fp16.h>
#include <math.h>

#define HD   512
#define BB   256
#define TT   200
#define DIN  64
#define DOUT 64
#define NCLS 10
#define LIPC 0.909f

// ---------------- workspace layout (bytes) ----------------
#define GS_BYTES    407552
#define OFF2_WX     0
#define OFF2_WEMB   16384
#define OFF2_WF1    278528
#define OFF2_WF2    409600
#define OFF2_WOUT   540672
#define OFF2_WDEC   671744         // 256 kp x 64
#define NPACK       688128         // uints in W2
#define NFU         16384          // WfuP uints

// new-path extras (byte offsets from ws base)
#define OFF_GF      3227648ULL     // 512x512 f32
#define OFF_HF      4276224ULL
#define OFF_MF      5324800ULL
#define OFF_T64     6373376ULL     // 64x512 f32
#define OFF_F1F     6504448ULL
#define OFF_MDF     6635520ULL     // 512x64 f32
#define OFF_MCF     6766592ULL     // 512x16 f32
#define OFF_C1      6799360ULL
#define OFF_H0      6801408ULL
#define OFF_M0      6803456ULL
#define OFF_MD0     6805504ULL
#define OFF_MC0     6805760ULL
#define OFF_M2      6805824ULL     // 256x512 uint
#define OFF_G2      7330112ULL
#define OFF_F1P     7854400ULL     // 32x512 uint
#define OFF_MDP     7919936ULL     // 256x64 uint
#define OFF_MCP     7985472ULL     // 256x16 uint
#define OFF_WC16    8001856ULL     // 256x16 uint
#define OFF_E1H     8018240ULL     // 50944x512 half
#define OFF_EDF     60184896ULL    // 50944x64 f32
#define OFF_ECF     73226560ULL    // 50944x16 f32
#define WS_NEED     76486976ULL

__device__ __forceinline__ float lipswish(float x) {
    return LIPC * x / (1.0f + expf(-x));
}

typedef _Float16 h2_t __attribute__((ext_vector_type(2)));

__device__ __forceinline__ float fdot2u(unsigned a, unsigned b, float c) {
    return __builtin_amdgcn_fdot2(__builtin_bit_cast(h2_t, a),
                                  __builtin_bit_cast(h2_t, b), c, false);
}

__device__ __forceinline__ unsigned packh2(float a, float b) {
    __half2 hp = __floats2half2_rn(a, b);
    return __builtin_bit_cast(unsigned, hp);
}

__device__ __forceinline__ void pack_store(float v, unsigned* dstH, int j) {
    float other = __shfl_xor(v, 1, 64);
    if ((j & 1) == 0) dstH[j >> 1] = packh2(v, other);
}

// ---------------------------------------------------------------------------
// fp32 partial matvec
// ---------------------------------------------------------------------------
template<int K>
__device__ __forceinline__ void mv_part(const float* __restrict__ W,
                                        const float* src, float* part, int j)
{
    const int g = j >> 7, c = j & 127;
    const int kpg = K >> 2;
    const int k0 = g * kpg;
    const float4* __restrict__ W4 = (const float4*)W;
    float4 acc; acc.x = acc.y = acc.z = acc.w = 0.f;
#pragma unroll 2
    for (int k = k0; k < k0 + kpg; k += 4) {
        float4 a  = *(const float4*)(src + k);
        float4 w0 = W4[(size_t)(k + 0) * 128 + c];
        float4 w1 = W4[(size_t)(k + 1) * 128 + c];
        float4 w2 = W4[(size_t)(k + 2) * 128 + c];
        float4 w3 = W4[(size_t)(k + 3) * 128 + c];
        acc.x = fmaf(a.x, w0.x, acc.x); acc.y = fmaf(a.x, w0.y, acc.y);
        acc.z = fmaf(a.x, w0.z, acc.z); acc.w = fmaf(a.x, w0.w, acc.w);
        acc.x = fmaf(a.y, w1.x, acc.x); acc.y = fmaf(a.y, w1.y, acc.y);
        acc.z = fmaf(a.y, w1.z, acc.z); acc.w = fmaf(a.y, w1.w, acc.w);
        acc.x = fmaf(a.z, w2.x, acc.x); acc.y = fmaf(a.z, w2.y, acc.y);
        acc.z = fmaf(a.z, w2.z, acc.z); acc.w = fmaf(a.z, w2.w, acc.w);
        acc.x = fmaf(a.w, w3.x, acc.x); acc.y = fmaf(a.w, w3.y, acc.y);
        acc.z = fmaf(a.w, w3.z, acc.z); acc.w = fmaf(a.w, w3.w, acc.w);
    }
    *(float4*)(part + g * HD + 4 * c) = acc;
}
#define MV_REDUCE4(bias, j) ((bias)[j] + part[j] + part[HD + (j)] + part[2 * HD + (j)] + part[3 * HD + (j)])
#define MV_REDUCE8(bias, j) ((bias)[j] + ((part[j] + part[HD + (j)]) + (part[2 * HD + (j)] + part[3 * HD + (j)])) \
                           + ((part[4 * HD + (j)] + part[5 * HD + (j)]) + (part[6 * HD + (j)] + part[7 * HD + (j)])))

// ---------------------------------------------------------------------------
// device bodies shared by stageA and the fallback kernels
// ---------------------------------------------------------------------------
__device__ __forceinline__ void cvt_body(int bid, int j,
    const float* W_X, const float* W_emb, const float* Wf1, const float* Wf2,
    const float* W_out, const float* W_dec, unsigned* dst)
{
    size_t e = ((size_t)bid << 9) + j;
    const float* src; size_t off2; int csh;
    if      (bid < 32)   { src = W_X;   off2 = OFF2_WX;   csh = 9; }
    else if (bid < 544)  { src = W_emb; off2 = OFF2_WEMB; csh = 9; }
    else if (bid < 800)  { src = Wf1;   off2 = OFF2_WF1;  csh = 9; }
    else if (bid < 1056) { src = Wf2;   off2 = OFF2_WF2;  csh = 9; }
    else if (bid < 1312) { src = W_out; off2 = OFF2_WOUT; csh = 9; }
    else                 { src = W_dec; off2 = OFF2_WDEC; csh = 6; }
    size_t e2 = e - off2;
    size_t kp = e2 >> csh;
    size_t c  = e2 & (((size_t)1 << csh) - 1);
    size_t C  = (size_t)1 << csh;
    dst[e] = packh2(src[(2 * kp) * C + c], src[(2 * kp + 1) * C + c]);
}

__device__ __forceinline__ void fuse_body(int fb, int j,
    const float* W_X, const float* W_emb, const float* b_X, const float* b_emb,
    unsigned* WfuP, float* bias1)
{
    if (fb < 32) {
        const int k0 = fb * 2;
        float a0 = 0.f, a1 = 0.f;
#pragma unroll 4
        for (int n = 0; n < HD; ++n) {
            float w = W_emb[(size_t)(HD + n) * HD + j];
            a0 = fmaf(W_X[(size_t)k0 * HD + n],       w, a0);
            a1 = fmaf(W_X[(size_t)(k0 + 1) * HD + n], w, a1);
        }
        WfuP[(fb << 9) + j] = packh2(a0, a1);
    } else {
        float a0 = 0.f;
#pragma unroll 4
        for (int n = 0; n < HD; ++n)
            a0 = fmaf(b_X[n], W_emb[(size_t)(HD + n) * HD + j], a0);
        bias1[j] = a0 + b_emb[j];
    }
}

__device__ __forceinline__ void g_body(int t, int j, float* smem,
    const float* times, const float* W_noise, const float* b_noise,
    const float* Wg1, const float* bg1, const float* Wg2, const float* bg2,
    float* gs)
{
    float* tt   = smem;
    float* hh   = smem + HD;
    float* part = smem + 2 * HD;      // 4*HD floats
    float tv = times[t];
    tt[j] = tv * W_noise[j] + b_noise[j];
    __syncthreads();
    mv_part<HD>(Wg1, tt, part, j);
    __syncthreads();
    hh[j] = lipswish(MV_REDUCE4(bg1, j));
    __syncthreads();
    mv_part<HD>(Wg2, hh, part, j);
    __syncthreads();
    float dt = times[t + 1] - times[t];
    gs[t * HD + j] = MV_REDUCE4(bg2, j) * sqrtf(dt);
}

// tiled 8-row fp32 GEMM: C rows r0..r0+7 = A rows @ B (512x512). As = 8*HD LDS.
__device__ __forceinline__ void mm8_body(const float* __restrict__ A,
    const float* __restrict__ B, float* __restrict__ C, int r0, int j, float* As)
{
#pragma unroll
    for (int r = 0; r < 8; ++r) As[r * HD + j] = A[(size_t)(r0 + r) * HD + j];
    __syncthreads();
    float acc[8];
#pragma unroll
    for (int r = 0; r < 8; ++r) acc[r] = 0.f;
#pragma unroll 4
    for (int n = 0; n < HD; ++n) {
        float bv = B[(size_t)n * HD + j];
#pragma unroll
        for (int r = 0; r < 8; ++r) acc[r] = fmaf(As[r * HD + n], bv, acc[r]);
    }
#pragma unroll
    for (int r = 0; r < 8; ++r) C[(size_t)(r0 + r) * HD + j] = acc[r];
}

// ---------------------------------------------------------------------------
// stageA: cvt | fuse | g | G=We_y@Wf1 | H=Wf2@W_out | T64=W_X@We_x | h0
// grid = 1713 x 512
// ---------------------------------------------------------------------------
__global__ __launch_bounds__(512) void stageA(
    const float* __restrict__ W_X,  const float* __restrict__ W_emb,
    const float* __restrict__ Wf1,  const float* __restrict__ Wf2,
    const float* __restrict__ W_out, const float* __restrict__ W_dec,
    const float* __restrict__ b_X,  const float* __restrict__ b_emb,
    const float* __restrict__ times, const float* __restrict__ W_noise,
    const float* __restrict__ b_noise, const float* __restrict__ Wg1,
    const float* __restrict__ bg1, const float* __restrict__ Wg2,
    const float* __restrict__ bg2,
    const float* __restrict__ bf2, const float* __restrict__ b_out,
    unsigned* __restrict__ W2, unsigned* __restrict__ WfuP,
    float* __restrict__ bias1, float* __restrict__ gs,
    float* __restrict__ Gf, float* __restrict__ Hf,
    float* __restrict__ T64f, float* __restrict__ h0)
{
    __shared__ float smem[8 * HD];   // 16 KB
    const int bid = blockIdx.x;
    const int j   = threadIdx.x;
    if (bid < 1344) {
        cvt_body(bid, j, W_X, W_emb, Wf1, Wf2, W_out, W_dec, W2);
    } else if (bid < 1377) {
        fuse_body(bid - 1344, j, W_X, W_emb, b_X, b_emb, WfuP, bias1);
    } else if (bid < 1576) {
        g_body(bid - 1377, j, smem, times, W_noise, b_noise, Wg1, bg1, Wg2, bg2, gs);
    } else if (bid < 1640) {
        mm8_body(W_emb, Wf1, Gf, (bid - 1576) * 8, j, smem);
    } else if (bid < 1704) {
        mm8_body(Wf2, W_out, Hf, (bid - 1640) * 8, j, smem);
    } else if (bid < 1712) {
        mm8_body(W_X, W_emb + (size_t)HD * HD, T64f, (bid - 1704) * 8, j, smem);
    } else {
        smem[j] = bf2[j];
        __syncthreads();
        float acc = 0.f;
#pragma unroll 4
        for (int n = 0; n < HD; ++n) acc = fmaf(smem[n], W_out[(size_t)n * HD + j], acc);
        h0[j] = acc + b_out[j];
    }
}

// ---------------------------------------------------------------------------
// stageB: M=H@G | F1=T64@Wf1 | Md=H@Wd + Mc=H@Wc | m0 | md0/mc0 | c1
// grid = 139 x 512
// ---------------------------------------------------------------------------
__global__ __launch_bounds__(512) void stageB(
    const float* __restrict__ Gf, const float* __restrict__ Hf,
    const float* __restrict__ T64f, const float* __restrict__ Wf1,
    const float* __restrict__ W_dec, const float* __restrict__ W_cls,
    const float* __restrict__ bias1, const float* __restrict__ bf1,
    const float* __restrict__ h0,
    float* __restrict__ Mf, float* __restrict__ F1f,
    float* __restrict__ MdF, float* __restrict__ McF,
    float* __restrict__ m0, float* __restrict__ md0, float* __restrict__ mc0,
    float* __restrict__ c1)
{
    __shared__ float smem[8 * HD];   // 16 KB
    const int bid = blockIdx.x;
    const int j   = threadIdx.x;
    if (bid < 64) {
        mm8_body(Hf, Gf, Mf, bid * 8, j, smem);
    } else if (bid < 72) {
        mm8_body(T64f, Wf1, F1f, (bid - 64) * 8, j, smem);
    } else if (bid < 136) {
        const int r0 = (bid - 72) * 8;
#pragma unroll
        for (int r = 0; r < 8; ++r) smem[r * HD + j] = Hf[(size_t)(r0 + r) * HD + j];
        __syncthreads();
        {
            const int rr = j >> 6, c = j & 63;
            float acc = 0.f;
#pragma unroll 4
            for (int n = 0; n < HD; ++n)
                acc = fmaf(smem[rr * HD + n], W_dec[(size_t)n * 64 + c], acc);
            MdF[(size_t)(r0 + rr) * 64 + c] = acc;
        }
        if (j < 128) {
            const int rr = j >> 4, cc = j & 15;
            float acc = 0.f;
            if (cc < NCLS) {
#pragma unroll 4
                for (int n = 0; n < HD; ++n)
                    acc = fmaf(smem[rr * HD + n], W_cls[(size_t)n * NCLS + cc], acc);
            }
            McF[(size_t)(r0 + rr) * 16 + cc] = acc;
        }
    } else if (bid == 136) {
        smem[j] = h0[j];
        __syncthreads();
        float acc = 0.f;
#pragma unroll 4
        for (int n = 0; n < HD; ++n) acc = fmaf(smem[n], Gf[(size_t)n * HD + j], acc);
        m0[j] = acc;
    } else if (bid == 137) {
        smem[j] = h0[j];
        __syncthreads();
        if (j < 64) {
            float acc = 0.f;
#pragma unroll 4
            for (int n = 0; n < HD; ++n) acc = fmaf(smem[n], W_dec[(size_t)n * 64 + j], acc);
            md0[j] = acc;
        } else if (j < 80) {
            int c = j - 64;
            float acc = 0.f;
            if (c < NCLS) {
                for (int n = 0; n < HD; ++n) acc = fmaf(smem[n], W_cls[(size_t)n * NCLS + c], acc);
            }
            mc0[c] = acc;
        }
    } else {
        smem[j] = bias1[j];
        __syncthreads();
        float acc = 0.f;
#pragma unroll 4
        for (int n = 0; n < HD; ++n) acc = fmaf(smem[n], Wf1[(size_t)n * HD + j], acc);
        c1[j] = acc + bf1[j];
    }
}

// ---------------------------------------------------------------------------
// fallback-only standalone kernels (unchanged from verified R3/R4 path)
// ---------------------------------------------------------------------------
__global__ __launch_bounds__(512) void cvt_kernel(
    const float* __restrict__ W_X,  const float* __restrict__ W_emb,
    const float* __restrict__ Wf1,  const float* __restrict__ Wf2,
    const float* __restrict__ W_out, const float* __restrict__ W_dec,
    unsigned* __restrict__ dst)
{
    cvt_body(blockIdx.x, threadIdx.x, W_X, W_emb, Wf1, Wf2, W_out, W_dec, dst);
}

__global__ __launch_bounds__(512) void fuse_kernel(
    const float* __restrict__ W_X, const float* __restrict__ W_emb,
    const float* __restrict__ b_X, const float* __restrict__ b_emb,
    unsigned* __restrict__ WfuP, float* __restrict__ bias1)
{
    fuse_body(blockIdx.x, threadIdx.x, W_X, W_emb, b_X, b_emb, WfuP, bias1);
}

__global__ __launch_bounds__(512) void g_kernel(
    const float* __restrict__ times, const float* __restrict__ W_noise,
    const float* __restrict__ b_noise, const float* __restrict__ Wg1,
    const float* __restrict__ bg1, const float* __restrict__ Wg2,
    const float* __restrict__ bg2, float* __restrict__ gs)
{
    __shared__ float smem[6 * HD];
    g_body(blockIdx.x, threadIdx.x, smem, times, W_noise, b_noise,
           Wg1, bg1, Wg2, bg2, gs);
}

// ---------------------------------------------------------------------------
// packall: fp32 -> half2-pair packs for all new-path matrices. grid 592 x 512.
// ---------------------------------------------------------------------------
__global__ __launch_bounds__(512) void packall(
    const float* __restrict__ Mf, const float* __restrict__ Gf,
    const float* __restrict__ F1f, const float* __restrict__ MdF,
    const float* __restrict__ McF, const float* __restrict__ Wc,
    unsigned* __restrict__ M2, unsigned* __restrict__ G2,
    unsigned* __restrict__ F1P, unsigned* __restrict__ MdP,
    unsigned* __restrict__ McP, unsigned* __restrict__ Wc16)
{
    int bid = blockIdx.x, j = threadIdx.x;
    if (bid < 256) {
        int kp = bid;
        M2[(kp << 9) + j] = packh2(Mf[(size_t)(2 * kp) * HD + j], Mf[(size_t)(2 * kp + 1) * HD + j]);
    } else if (bid < 512) {
        int kp = bid - 256;
        G2[(kp << 9) + j] = packh2(Gf[(size_t)(2 * kp) * HD + j], Gf[(size_t)(2 * kp + 1) * HD + j]);
    } else if (bid < 544) {
        int kp = bid - 512;
        F1P[(kp << 9) + j] = packh2(F1f[(size_t)(2 * kp) * HD + j], F1f[(size_t)(2 * kp + 1) * HD + j]);
    } else if (bid < 576) {
        int e = (bid - 544) * 512 + j;
        int kp = e >> 6, c = e & 63;
        MdP[e] = packh2(MdF[(size_t)(2 * kp) * 64 + c], MdF[(size_t)(2 * kp + 1) * 64 + c]);
    } else if (bid < 584) {
        int e = (bid - 576) * 512 + j;
        int kp = e >> 4, c = e & 15;
        McP[e] = packh2(McF[(size_t)(2 * kp) * 16 + c], McF[(size_t)(2 * kp + 1) * 16 + c]);
    } else {
        int e = (bid - 584) * 512 + j;
        int kp = e >> 4, c = e & 15;
        float v0 = (c < NCLS) ? Wc[(size_t)(2 * kp) * NCLS + c] : 0.f;
        float v1 = (c < NCLS) ? Wc[(size_t)(2 * kp + 1) * NCLS + c] : 0.f;
        Wc16[e] = packh2(v0, v1);
    }
}

// ---------------------------------------------------------------------------
// eg: E1 = dW@G (half), Ed = dW@W_dec (f32), Ec = dW@W_cls16 (f32)
// ---------------------------------------------------------------------------
__global__ __launch_bounds__(512) void eg_kernel(
    const float* __restrict__ noise, const float* __restrict__ gs,
    const unsigned* __restrict__ G2, const unsigned* __restrict__ Wd2,
    const unsigned* __restrict__ Wc16,
    __half* __restrict__ E1h, float* __restrict__ Edf, float* __restrict__ Ecf)
{
    const int r0 = blockIdx.x * 32;
    const int t  = r0 >> 8;
    const int j  = threadIdx.x;
    __shared__ unsigned dWH[32 * 256];   // [rr*256 + kp]

#pragma unroll
    for (int i = 0; i < 16; ++i) {
        int e = i * 512 + j;
        int rr = e >> 8, kp = e & 255;
        float2 nz = *(const float2*)(noise + (size_t)(r0 + rr) * HD + 2 * kp);
        float2 gv = *(const float2*)(gs + (size_t)t * HD + 2 * kp);
        dWH[rr * 256 + kp] = packh2(nz.x * gv.x, nz.y * gv.y);
    }
    __syncthreads();

    {
        const int rg = j >> 7, cq = j & 127;
        float acc[8][4];
#pragma unroll
        for (int s = 0; s < 8; ++s)
#pragma unroll
            for (int c = 0; c < 4; ++c) acc[s][c] = 0.f;
#pragma unroll 2
        for (int kp = 0; kp < 256; ++kp) {
            uint4 w = *(const uint4*)(G2 + ((size_t)kp << 9) + (cq << 2));
#pragma unroll
            for (int s = 0; s < 8; ++s) {
                unsigned a = dWH[(rg * 8 + s) * 256 + kp];
                acc[s][0] = fdot2u(a, w.x, acc[s][0]);
                acc[s][1] = fdot2u(a, w.y, acc[s][1]);
                acc[s][2] = fdot2u(a, w.z, acc[s][2]);
                acc[s][3] = fdot2u(a, w.w, acc[s][3]);
            }
        }
#pragma unroll
        for (int s = 0; s < 8; ++s) {
            size_t row = r0 + rg * 8 + s;
            *(unsigned*)(E1h + row * HD + 4 * cq)     = packh2(acc[s][0], acc[s][1]);
            *(unsigned*)(E1h + row * HD + 4 * cq + 2) = packh2(acc[s][2], acc[s][3]);
        }
    }
    {
        const int rgrp = j >> 6, c = j & 63;
        float ad[4] = {0.f, 0.f, 0.f, 0.f};
#pragma unroll 4
        for (int kp = 0; kp < 256; ++kp) {
            unsigned wv = Wd2[(kp << 6) + c];
#pragma unroll
            for (int s = 0; s < 4; ++s)
                ad[s] = fdot2u(dWH[(rgrp * 4 + s) * 256 + kp], wv, ad[s]);
        }
#pragma unroll
        for (int s = 0; s < 4; ++s)
            Edf[(size_t)(r0 + rgrp * 4 + s) * 64 + c] = ad[s];
    }
    {
        const int rr = j >> 4, c = j & 15;
        float ac = 0.f;
#pragma unroll 4
        for (int kp = 0; kp < 256; ++kp)
            ac = fdot2u(dWH[rr * 256 + kp], Wc16[(kp << 4) + c], ac);
        Ecf[(size_t)(r0 + rr) * 16 + c] = ac;
    }
}

// ---------------------------------------------------------------------------
// dot2 matvec (fallback scan)
// ---------------------------------------------------------------------------
template<int KP>
__device__ __forceinline__ void mv_dot2(const unsigned* __restrict__ W2,
                                        const unsigned* actH, float* part, int j)
{
    const int g = j >> 6, o8 = (j & 63) << 3;
    constexpr int kpg = KP / 8;
    const int kp0 = g * kpg;
    float acc[8];
#pragma unroll
    for (int i = 0; i < 8; ++i) acc[i] = 0.f;
#pragma unroll 8
    for (int kp = kp0; kp < kp0 + kpg; ++kp) {
        unsigned ap = actH[kp];
        uint4 w0 = *(const uint4*)(W2 + ((size_t)kp << 9) + o8);
        uint4 w1 = *(const uint4*)(W2 + ((size_t)kp << 9) + o8 + 4);
        acc[0] = fdot2u(ap, w0.x, acc[0]);
        acc[1] = fdot2u(ap, w0.y, acc[1]);
        acc[2] = fdot2u(ap, w0.z, acc[2]);
        acc[3] = fdot2u(ap, w0.w, acc[3]);
        acc[4] = fdot2u(ap, w1.x, acc[4]);
        acc[5] = fdot2u(ap, w1.y, acc[5]);
        acc[6] = fdot2u(ap, w1.z, acc[6]);
        acc[7] = fdot2u(ap, w1.w, acc[7]);
    }
    float* pb = part + (g << 9) + o8;
    *(float4*)(pb)     = make_float4(acc[0], acc[1], acc[2], acc[3]);
    *(float4*)(pb + 4) = make_float4(acc[4], acc[5], acc[6], acc[7]);
}

// ---------------------------------------------------------------------------
// scan_fast pipeline helpers: chunk = 4 kp (8 uint4 loads, 32 fdot2).
// All indices compile-time after unroll -> stays in registers.
// ---------------------------------------------------------------------------
__device__ __forceinline__ void m_ld(uint4 (&buf)[8], const unsigned* bp, int c)
{
    const unsigned* p = bp + ((size_t)(c * 4) << 9);
#pragma unroll
    for (int r = 0; r < 4; ++r) {
        buf[2 * r]     = *(const uint4*)(p + r * 512);
        buf[2 * r + 1] = *(const uint4*)(p + r * 512 + 4);
    }
}

__device__ __forceinline__ void m_fd(const uint4 (&buf)[8], const unsigned* actH,
                                     int kp0, int c, float (&f)[8])
{
#pragma unroll
    for (int r = 0; r < 4; ++r) {
        unsigned ap = actH[kp0 + c * 4 + r];
        f[0] = fdot2u(ap, buf[2 * r].x, f[0]);
        f[1] = fdot2u(ap, buf[2 * r].y, f[1]);
        f[2] = fdot2u(ap, buf[2 * r].z, f[2]);
        f[3] = fdot2u(ap, buf[2 * r].w, f[3]);
        f[4] = fdot2u(ap, buf[2 * r + 1].x, f[4]);
        f[5] = fdot2u(ap, buf[2 * r + 1].y, f[5]);
        f[6] = fdot2u(ap, buf[2 * r + 1].z, f[6]);
        f[7] = fdot2u(ap, buf[2 * r + 1].w, f[7]);
    }
}

__device__ __forceinline__ float md4(const unsigned* actH, const unsigned* MdL,
                                     int kp0, int s, int mdc, float dmv)
{
#pragma unroll
    for (int r = 0; r < 4; ++r) {
        int kp = kp0 + s * 4 + r;
        dmv = fdot2u(actH[kp], MdL[(kp << 6) + mdc], dmv);
    }
    return dmv;
}

// ---------------------------------------------------------------------------
// scan_fast: conjugated state, pipelined M-GEMV.
// __launch_bounds__(512, 2): 8 waves/block = 2 waves/SIMD -> 256-VGPR budget,
// so the 3 chunk buffers (96 VGPRs) stay in registers (R6 spilled at the
// default 128 cap: FETCH 2.4 GB / WRITE 363 MB of scratch traffic).
// ---------------------------------------------------------------------------
__global__ __launch_bounds__(512, 2) void scan_fast(
    const float* __restrict__ coeffs, const float* __restrict__ times,
    const int* __restrict__ mask,
    const unsigned* __restrict__ M2G, const unsigned* __restrict__ F1P,
    const unsigned* __restrict__ MdP, const unsigned* __restrict__ McP,
    const float* __restrict__ c1G, const float* __restrict__ m0G,
    const float* __restrict__ md0G, const float* __restrict__ mc0G,
    const float* __restrict__ GfG,
    const float* __restrict__ W_init, const float* __restrict__ b_init,
    const float* __restrict__ W_dec, const float* __restrict__ b_dec,
    const float* __restrict__ W_cls, const float* __restrict__ b_cls,
    const __half* __restrict__ E1h, const float* __restrict__ Edf,
    const float* __restrict__ Ecf,
    float* __restrict__ out)
{
    const int b = blockIdx.x;
    const int j = threadIdx.x;

    __shared__ __align__(16) unsigned F1L[32 * HD];     // 64 KB
    __shared__ __align__(16) unsigned MdL[32 * HD];     // 64 KB (256 kp x 64)
    __shared__ __align__(16) float    part[8 * HD];     // 16 KB
    __shared__ __align__(16) float    y0L[HD];
    __shared__ __align__(16) float    c1L[HD];
    __shared__ __align__(16) float    m0L[HD];
    __shared__ __align__(16) float    partd[512];
    __shared__ __align__(16) float    partw[256];
    __shared__ __align__(16) unsigned actH[HD / 2];
    __shared__ float    tl[TT];
    __shared__ float    md0L[64], bdecL[64];
    __shared__ float    vL[64];
    __shared__ float    avec[DIN];
    __shared__ unsigned avecH[DIN / 2];
    __shared__ float    mc0L[16], wL[16], wfinL[16];
    __shared__ int      lidx_s;

    if (j < TT) tl[j] = times[j];
#pragma unroll
    for (int i = 0; i < 32; ++i) F1L[(i << 9) + j] = F1P[(i << 9) + j];
#pragma unroll
    for (int i = 0; i < 32; ++i) MdL[(i << 9) + j] = MdP[(i << 9) + j];
    c1L[j] = c1G[j];
    m0L[j] = m0G[j];
    if (j < 64) { md0L[j] = md0G[j]; bdecL[j] = b_dec[j]; }
    if (j < 16) { mc0L[j] = mc0G[j]; wL[j] = 0.f; wfinL[j] = 0.f; }

    // per-row length
    {
        int m = 0;
        for (int t = j; t < TT; t += 512) m += mask[b * TT + t];
        part[j] = (float)m;
        __syncthreads();
        for (int s = 256; s > 0; s >>= 1) {
            if (j < s) part[j] += part[j + s];
            __syncthreads();
        }
        if (j == 0) lidx_s = (int)part[0] - 1;
        __syncthreads();
    }
    const int lidx = lidx_s;

    // y0 = a0@W_init + b_init
    if (j < DIN / 4)
        ((float4*)avec)[j] = ((const float4*)(coeffs + (size_t)b * (TT - 1) * 4 * DIN))[j];
    __syncthreads();
    mv_part<DIN>(W_init, avec, part, j);
    __syncthreads();
    y0L[j] = MV_REDUCE4(b_init, j);
    __syncthreads();

    // q0 = y0@G (fp32), v0 = y0@W_dec, w0 = y0@W_cls
    mv_part<HD>(GfG, y0L, part, j);
    if (j < 64) {
        float acc = 0.f;
#pragma unroll 4
        for (int n = 0; n < HD; ++n) acc = fmaf(y0L[n], W_dec[(size_t)n * 64 + j], acc);
        vL[j] = acc;
        out[((size_t)b * TT) * DOUT + j] = acc + b_dec[j];
    } else if (j >= 64 && j < 64 + NCLS) {
        int c = j - 64;
        float acc = 0.f;
#pragma unroll 4
        for (int n = 0; n < HD; ++n) acc = fmaf(y0L[n], W_cls[(size_t)n * NCLS + c], acc);
        wL[c] = acc;
    }
    __syncthreads();
    float q = part[j] + part[HD + j] + part[2 * HD + j] + part[3 * HD + j];
    if (j < 16 && lidx == 0) wfinL[j] = wL[j];
    __syncthreads();

    const int g8  = j >> 6;
    const int o8  = (j & 63) << 3;
    const int kp0 = g8 * 32;
    const int mdc = j & 63;
    const unsigned* bp = M2G + ((size_t)kp0 << 9) + o8;

    // ---- main scan ----
    for (int t = 0; t < TT - 1; ++t) {
        const size_t rbase = (size_t)t * BB + b;
        // early HBM loads (consumed after S3-phase reduce)
        unsigned short e1u = ((const unsigned short*)E1h)[rbase * HD + j];
        float edv = Edf[rbase * 64 + (j & 63)];
        float ecv = Ecf[rbase * 16 + (j & 15)];
        if (j < 32) {
            float2 a2 = ((const float2*)(coeffs + ((size_t)b * (TT - 1) + t) * 4 * DIN))[j];
            avecH[j] = packh2(a2.x, a2.y);
        }
        __syncthreads();   // S1
        {
            float sa = 0.f, sb = 0.f, sc = 0.f, sd = 0.f;
#pragma unroll
            for (int kp = 0; kp < 8; ++kp) {
                sa = fdot2u(avecH[kp],      F1L[((kp)      << 9) + j], sa);
                sb = fdot2u(avecH[kp + 8],  F1L[((kp + 8)  << 9) + j], sb);
                sc = fdot2u(avecH[kp + 16], F1L[((kp + 16) << 9) + j], sc);
                sd = fdot2u(avecH[kp + 24], F1L[((kp + 24) << 9) + j], sd);
            }
            float s = ((q + c1L[j]) + (sa + sb)) + (sc + sd);
            pack_store(lipswish(s), actH, j);
        }
        // prefetch first 3 chunks of M (addresses step-invariant, indep of actH)
        uint4 Ab[8], Bb[8], Cb[8];
        m_ld(Ab, bp, 0); m_ld(Bb, bp, 1); m_ld(Cb, bp, 2);
        __syncthreads();   // S2
        float f[8];
#pragma unroll
        for (int i = 0; i < 8; ++i) f[i] = 0.f;
        float dm0 = 0.f, dm1 = 0.f;
        m_fd(Ab, actH, kp0, 0, f); dm0 = md4(actH, MdL, kp0, 0, mdc, dm0); m_ld(Ab, bp, 3);
        m_fd(Bb, actH, kp0, 1, f); dm1 = md4(actH, MdL, kp0, 1, mdc, dm1); m_ld(Bb, bp, 4);
        m_fd(Cb, actH, kp0, 2, f); dm0 = md4(actH, MdL, kp0, 2, mdc, dm0); m_ld(Cb, bp, 5);
        m_fd(Ab, actH, kp0, 3, f); dm1 = md4(actH, MdL, kp0, 3, mdc, dm1); m_ld(Ab, bp, 6);
        m_fd(Bb, actH, kp0, 4, f); dm0 = md4(actH, MdL, kp0, 4, mdc, dm0); m_ld(Bb, bp, 7);
        m_fd(Cb, actH, kp0, 5, f); dm1 = md4(actH, MdL, kp0, 5, mdc, dm1);
        m_fd(Ab, actH, kp0, 6, f); dm0 = md4(actH, MdL, kp0, 6, mdc, dm0);
        m_fd(Bb, actH, kp0, 7, f); dm1 = md4(actH, MdL, kp0, 7, mdc, dm1);
        {
            float* pb2 = part + (g8 << 9) + o8;
            *(float4*)(pb2)     = make_float4(f[0], f[1], f[2], f[3]);
            *(float4*)(pb2 + 4) = make_float4(f[4], f[5], f[6], f[7]);
            partd[(g8 << 6) + mdc] = dm0 + dm1;
        }
        if (j < 256) {
            int gw = j >> 4, cw = j & 15;
            float wacc = 0.f;
#pragma unroll
            for (int i2 = 0; i2 < 16; ++i2) {
                int kp = gw * 16 + i2;
                wacc = fdot2u(actH[kp], McP[(kp << 4) + cw], wacc);
            }
            partw[(gw << 4) + cw] = wacc;
        }
        __syncthreads();   // S3
        {
            float dtv = tl[t + 1] - tl[t];
            float red = ((part[j] + part[HD + j]) + (part[2 * HD + j] + part[3 * HD + j]))
                      + ((part[4 * HD + j] + part[5 * HD + j]) + (part[6 * HD + j] + part[7 * HD + j]));
            q = q + dtv * (red + m0L[j]) + __half2float(__builtin_bit_cast(__half, e1u));
            if (j < 64) {
                float dv = 0.f;
#pragma unroll
                for (int g = 0; g < 8; ++g) dv += partd[(g << 6) + j];
                float vn = vL[j] + dtv * (dv + md0L[j]) + edv;
                vL[j] = vn;
                out[((size_t)b * TT + t + 1) * DOUT + j] = vn + bdecL[j];
            }
            if (j < 16) {
                float dw = 0.f;
#pragma unroll
                for (int g = 0; g < 16; ++g) dw += partw[(g << 4) + j];
                float wn = wL[j] + dtv * (dw + mc0L[j]) + ecv;
                wL[j] = wn;
                if (t + 1 == lidx) wfinL[j] = wn;
            }
        }
    }
    __syncthreads();
    if (j < NCLS)
        out[(size_t)BB * TT * DOUT + b * NCLS + j] = wfinL[j] + b_cls[j];
}

// ---------------------------------------------------------------------------
// FALLBACK scan (verified R3 kernel, used when ws is too small)
// ---------------------------------------------------------------------------
__device__ __forceinline__ void decode_store_d2(const unsigned* __restrict__ Wd2,
    const float* __restrict__ b_dec, const unsigned* yH, float* part, float* dscr,
    int j, float* __restrict__ outp)
{
    const int g = j >> 3, o8 = (j & 7) << 3;
    const int kp0 = g << 2;
    float acc[8];
#pragma unroll
    for (int i = 0; i < 8; ++i) acc[i] = 0.f;
#pragma unroll
    for (int kp = kp0; kp < kp0 + 4; ++kp) {
        unsigned ap = yH[kp];
        uint4 w0 = *(const uint4*)(Wd2 + ((size_t)kp << 6) + o8);
        uint4 w1 = *(const uint4*)(Wd2 + ((size_t)kp << 6) + o8 + 4);
        acc[0] = fdot2u(ap, w0.x, acc[0]);
        acc[1] = fdot2u(ap, w0.y, acc[1]);
        acc[2] = fdot2u(ap, w0.z, acc[2]);
        acc[3] = fdot2u(ap, w0.w, acc[3]);
        acc[4] = fdot2u(ap, w1.x, acc[4]);
        acc[5] = fdot2u(ap, w1.y, acc[5]);
        acc[6] = fdot2u(ap, w1.z, acc[6]);
        acc[7] = fdot2u(ap, w1.w, acc[7]);
    }
    float* pb = part + (g << 6) + o8;
    *(float4*)(pb)     = make_float4(acc[0], acc[1], acc[2], acc[3]);
    *(float4*)(pb + 4) = make_float4(acc[4], acc[5], acc[6], acc[7]);
    __syncthreads();
    {
        int o2 = j >> 6, col = j & 63;
        float s = 0.f;
#pragma unroll
        for (int i = 0; i < 8; ++i) s += part[((o2 << 3) + i) * 64 + col];
        dscr[(o2 << 6) + col] = s;
    }
    __syncthreads();
    if (j < DOUT) {
        float s = b_dec[j];
#pragma unroll
        for (int i = 0; i < 8; ++i) s += dscr[(i << 6) + j];
        outp[j] = s;
    }
}

__global__ __launch_bounds__(512) void scan_fb(
    const float* __restrict__ coeffs, const float* __restrict__ times,
    const float* __restrict__ noise, const float* __restrict__ bias1,
    const float* __restrict__ bf1, const float* __restrict__ bf2,
    const float* __restrict__ b_out,
    const float* __restrict__ W_init, const float* __restrict__ b_init,
    const float* __restrict__ b_dec,
    const float* __restrict__ W_cls, const float* __restrict__ b_cls,
    const int* __restrict__ mask, const float* __restrict__ gs,
    const unsigned* __restrict__ W2, const unsigned* __restrict__ WfuG,
    float* __restrict__ out)
{
    const int b = blockIdx.x;
    const int j = threadIdx.x;

    const unsigned* __restrict__ W_emb_2 = W2 + OFF2_WEMB;
    const unsigned* __restrict__ Wf1_2   = W2 + OFF2_WF1;
    const unsigned* __restrict__ Wf2_2   = W2 + OFF2_WF2;
    const unsigned* __restrict__ W_out_2 = W2 + OFF2_WOUT;
    const unsigned* __restrict__ W_dec_2 = W2 + OFF2_WDEC;

    __shared__ float    yF[HD];
    __shared__ unsigned yH[HD / 2];
    __shared__ unsigned actAH[HD / 2];
    __shared__ unsigned actBH[HD / 2];
    __shared__ unsigned avecH[DIN / 2];
    __shared__ unsigned WfuL[32 * HD];
    __shared__ float    part[8 * HD];
    __shared__ float    dscr[HD];
    __shared__ float    avec[DIN];
    __shared__ float    zfin[HD];
    __shared__ float    tl[TT];
    __shared__ int      last_idx_s;

    if (j < TT) tl[j] = times[j];
#pragma unroll
    for (int i = 0; i < 32; ++i) WfuL[i * 512 + j] = WfuG[i * 512 + j];
    {
        int m = 0;
        for (int t = j; t < TT; t += 512) m += mask[b * TT + t];
        part[j] = (float)m;
        __syncthreads();
        for (int s = 256; s > 0; s >>= 1) {
            if (j < s) part[j] += part[j + s];
            __syncthreads();
        }
        if (j == 0) last_idx_s = (int)part[0] - 1;
        __syncthreads();
    }
    const int last_idx = last_idx_s;

    if (j < DIN / 4)
        ((float4*)avec)[j] = ((const float4*)(coeffs + (size_t)b * (TT - 1) * 4 * DIN))[j];
    __syncthreads();
    mv_part<DIN>(W_init, avec, part, j);
    __syncthreads();
    {
        float y = MV_REDUCE4(b_init, j);
        yF[j] = y;
        pack_store(y, yH, j);
        if (last_idx == 0) zfin[j] = y;
    }
    __syncthreads();
    decode_store_d2(W_dec_2, b_dec, yH, part, dscr, j, out + ((size_t)b * TT) * DOUT);

    for (int t = 0; t < TT - 1; ++t) {
        if (j < DIN / 2) {
            float2 a2 = ((const float2*)(coeffs + ((size_t)b * (TT - 1) + t) * 4 * DIN))[j];
            avecH[j] = packh2(a2.x, a2.y);
        }
        __syncthreads();
        mv_dot2<HD / 2>(W_emb_2, yH, part, j);
        __syncthreads();
        {
            float s = MV_REDUCE8(bias1, j);
#pragma unroll
            for (int kp = 0; kp < 32; ++kp)
                s = fdot2u(avecH[kp], WfuL[(kp << 9) + j], s);
            pack_store(s, actAH, j);
        }
        __syncthreads();
        mv_dot2<HD / 2>(Wf1_2, actAH, part, j);
        __syncthreads();
        pack_store(lipswish(MV_REDUCE8(bf1, j)), actBH, j);
        __syncthreads();
        mv_dot2<HD / 2>(Wf2_2, actBH, part, j);
        __syncthreads();
        pack_store(MV_REDUCE8(bf2, j), actAH, j);
        __syncthreads();
        mv_dot2<HD / 2>(W_out_2, actAH, part, j);
        __syncthreads();
        {
            float dr = MV_REDUCE8(b_out, j);
            float dtv = tl[t + 1] - tl[t];
            float yn = yF[j] + dr * dtv
                     + gs[(size_t)t * HD + j] * noise[((size_t)t * BB + b) * HD + j];
            yF[j] = yn;
            pack_store(yn, yH, j);
            if (t + 1 == last_idx) zfin[j] = yn;
        }
        __syncthreads();
        decode_store_d2(W_dec_2, b_dec, yH, part, dscr, j,
                        out + ((size_t)b * TT + (t + 1)) * DOUT);
    }
    __syncthreads();
    {
        int c = j & 15, seg = j >> 4;
        float p = 0.f;
        if (c < NCLS) {
#pragma unroll
            for (int k = seg * 16; k < seg * 16 + 16; ++k)
                p = fmaf(zfin[k], W_cls[k * NCLS + c], p);
        }
        part[j] = p;
        __syncthreads();
        if (j < NCLS) {
            float s = b_cls[j];
#pragma unroll
            for (int sg = 0; sg < 32; ++sg) s += part[sg * 16 + j];
            out[(size_t)BB * TT * DOUT + b * NCLS + j] = s;
        }
    }
}

extern "C" void kernel_launch(void* const* d_in, const int* in_sizes, int n_in,
                              void* d_out, int out_size, void* d_ws, size_t ws_size,
                              hipStream_t stream)
{
    const float* coeffs  = (const float*)d_in[0];
    const float* times   = (const float*)d_in[1];
    const float* noise   = (const float*)d_in[2];
    const float* W_X     = (const float*)d_in[3];
    const float* b_X     = (const float*)d_in[4];
    const float* W_emb   = (const float*)d_in[5];
    const float* b_emb   = (const float*)d_in[6];
    const float* Wf1     = (const float*)d_in[7];
    const float* bf1     = (const float*)d_in[8];
    const float* Wf2     = (const float*)d_in[9];
    const float* bf2     = (const float*)d_in[10];
    const float* W_out   = (const float*)d_in[11];
    const float* b_out   = (const float*)d_in[12];
    const float* W_noise = (const float*)d_in[13];
    const float* b_noise = (const float*)d_in[14];
    const float* Wg1     = (const float*)d_in[15];
    const float* bg1     = (const float*)d_in[16];
    const float* Wg2     = (const float*)d_in[17];
    const float* bg2     = (const float*)d_in[18];
    const float* W_init  = (const float*)d_in[19];
    const float* b_init  = (const float*)d_in[20];
    const float* W_dec   = (const float*)d_in[21];
    const float* b_dec   = (const float*)d_in[22];
    const float* W_cls   = (const float*)d_in[23];
    const float* b_cls   = (const float*)d_in[24];
    const int*   mask    = (const int*)d_in[25];

    char* ws = (char*)d_ws;
    float*    gs    = (float*)ws;
    unsigned* W2    = (unsigned*)(ws + GS_BYTES);
    unsigned* WfuP  = W2 + NPACK;
    float*    bias1 = (float*)(W2 + NPACK + NFU);
    float*    out   = (float*)d_out;

    if (ws_size >= WS_NEED) {
        float*    Gf   = (float*)(ws + OFF_GF);
        float*    Hf   = (float*)(ws + OFF_HF);
        float*    Mf   = (float*)(ws + OFF_MF);
        float*    T64f = (float*)(ws + OFF_T64);
        float*    F1f  = (float*)(ws + OFF_F1F);
        float*    MdF  = (float*)(ws + OFF_MDF);
        float*    McF  = (float*)(ws + OFF_MCF);
        float*    c1   = (float*)(ws + OFF_C1);
        float*    h0   = (float*)(ws + OFF_H0);
        float*    m0   = (float*)(ws + OFF_M0);
        float*    md0  = (float*)(ws + OFF_MD0);
        float*    mc0  = (float*)(ws + OFF_MC0);
        unsigned* M2   = (unsigned*)(ws + OFF_M2);
        unsigned* G2   = (unsigned*)(ws + OFF_G2);
        unsigned* F1P  = (unsigned*)(ws + OFF_F1P);
        unsigned* MdP  = (unsigned*)(ws + OFF_MDP);
        unsigned* McP  = (unsigned*)(ws + OFF_MCP);
        unsigned* Wc16 = (unsigned*)(ws + OFF_WC16);
        __half*   E1h  = (__half*)(ws + OFF_E1H);
        float*    Edf  = (float*)(ws + OFF_EDF);
        float*    Ecf  = (float*)(ws + OFF_ECF);
        unsigned* Wd2  = W2 + OFF2_WDEC;

        stageA<<<dim3(1713), dim3(512), 0, stream>>>(
            W_X, W_emb, Wf1, Wf2, W_out, W_dec, b_X, b_emb,
            times, W_noise, b_noise, Wg1, bg1, Wg2, bg2, bf2, b_out,
            W2, WfuP, bias1, gs, Gf, Hf, T64f, h0);

        stageB<<<dim3(139), dim3(512), 0, stream>>>(
            Gf, Hf, T64f, Wf1, W_dec, W_cls, bias1, bf1, h0,
            Mf, F1f, MdF, McF, m0, md0, mc0, c1);

        packall<<<dim3(592), dim3(512), 0, stream>>>(Mf, Gf, F1f, MdF, McF, W_cls,
                                                     M2, G2, F1P, MdP, McP, Wc16);

        eg_kernel<<<dim3((TT - 1) * BB / 32), dim3(512), 0, stream>>>(
            noise, gs, G2, Wd2, Wc16, E1h, Edf, Ecf);

        scan_fast<<<dim3(BB), dim3(512), 0, stream>>>(
            coeffs, times, mask, M2, F1P, MdP, McP, c1, m0, md0, mc0,
            Gf, W_init, b_init, W_dec, b_dec, W_cls, b_cls,
            E1h, Edf, Ecf, out);
    } else {
        cvt_kernel<<<dim3(NPACK / 512), dim3(512), 0, stream>>>(
            W_X, W_emb, Wf1, Wf2, W_out, W_dec, W2);
        fuse_kernel<<<dim3(33), dim3(512), 0, stream>>>(
            W_X, W_emb, b_X, b_emb, WfuP, bias1);
        g_kernel<<<dim3(TT - 1), dim3(512), 0, stream>>>(
            times, W_noise, b_noise, Wg1, bg1, Wg2, bg2, gs);
        scan_fb<<<dim3(BB), dim3(512), 0, stream>>>(
            coeffs, times, noise, bias1, bf1, bf2, b_out,
            W_init, b_init, b_dec, W_cls, b_cls, mask, gs, W2, WfuP, out);
    }
}